// Round 12
// baseline (2468.820 us; speedup 1.0000x reference)
//
#include <hip/hip_runtime.h>

// Problem constants
#define Sx 256
#define Bx 32
#define Hx 512
#define Gx 2048   // 4H
#define Lx 20
#define Rx 8192   // S*B

typedef __attribute__((ext_vector_type(8))) short short8;
typedef __attribute__((ext_vector_type(4))) float f32x4;
typedef __attribute__((ext_vector_type(16))) float f32x16;

__device__ __forceinline__ unsigned short f2bf(float f) {
  union { float f; unsigned u; } v; v.f = f;
  unsigned u = v.u;
  return (unsigned short)((u + 0x7fffu + ((u >> 16) & 1u)) >> 16);
}
__device__ __forceinline__ float bf2f(unsigned short h) {
  union { unsigned u; float f; } v; v.u = ((unsigned)h) << 16;
  return v.f;
}
__device__ __forceinline__ float bfh(unsigned long long x, int r) {
  return bf2f((unsigned short)((x >> (16 * r)) & 0xffffull));
}

// hardware transcendentals (v11+): ~3 ulp composite, orders below bf16 noise
__device__ __forceinline__ float fsigm(float x) {
  return __builtin_amdgcn_rcpf(1.0f + __builtin_amdgcn_exp2f(-1.44269504f * x));
}
__device__ __forceinline__ float ftanh(float x) {
  return __builtin_fmaf(-2.0f,
      __builtin_amdgcn_rcpf(1.0f + __builtin_amdgcn_exp2f(2.88539008f * x)), 1.0f);
}
#define L2E 1.44269504088896f
#define LN2 0.69314718055995f

// v17: async global->LDS staging, 16B per lane; XOR chunk-swizzle on both the
// per-lane global source and the ds_read chunk index (verified absmax 0.0).
#define GLD16(gp, lp) __builtin_amdgcn_global_load_lds( \
    (const __attribute__((address_space(1))) void*)(gp), \
    (__attribute__((address_space(3))) void*)(lp), 16, 0, 0)

// ---------------- pack / prep kernels ----------------

__global__ void k_pack_x(const float* __restrict__ x, unsigned short* __restrict__ xbf) {
  int tid = blockIdx.x * 256 + threadIdx.x;      // 0 .. S*B*H-1
  int h = tid & (Hx - 1);
  int r = tid >> 9;          // t*32+b
  int b = r & 31;
  int t = r >> 5;
  xbf[tid] = f2bf(x[(b * Sx + t) * Hx + h]);
}

// v16: single fused prep — all 8 weight casts (10M elems, 8/thread) + the 4
// bias adds. Segment table in 1M-element units: [0,1,2,3,4,6,8,9,10].
__global__ __launch_bounds__(256) void k_prep(
    const float* __restrict__ s0, const float* __restrict__ s1,
    const float* __restrict__ s2, const float* __restrict__ s3,
    const float* __restrict__ s4, const float* __restrict__ s5,
    const float* __restrict__ s6, const float* __restrict__ s7,
    unsigned short* __restrict__ d0, unsigned short* __restrict__ d1,
    unsigned short* __restrict__ d2, unsigned short* __restrict__ d3,
    unsigned short* __restrict__ d4, unsigned short* __restrict__ d5,
    unsigned short* __restrict__ d6, unsigned short* __restrict__ d7,
    const float* __restrict__ ba0, const float* __restrict__ bb0, float* __restrict__ bo0,
    const float* __restrict__ ba1, const float* __restrict__ bb1, float* __restrict__ bo1,
    const float* __restrict__ ba2, const float* __restrict__ bb2, float* __restrict__ bo2,
    const float* __restrict__ ba3, const float* __restrict__ bb3, float* __restrict__ bo3)
{
  const int blk = blockIdx.x;
  const int tid = threadIdx.x;
  if (blk < 5120) {
    const float* srcs[8] = { s0, s1, s2, s3, s4, s5, s6, s7 };
    unsigned short* dsts[8] = { d0, d1, d2, d3, d4, d5, d6, d7 };
    size_t e0 = ((size_t)blk * 256 + tid) * 8;
    int m = (int)(e0 >> 20);
    int seg; size_t base;
    if (m < 4)      { seg = m; base = (size_t)m << 20; }
    else if (m < 6) { seg = 4; base = (size_t)4 << 20; }
    else if (m < 8) { seg = 5; base = (size_t)6 << 20; }
    else if (m == 8){ seg = 6; base = (size_t)8 << 20; }
    else            { seg = 7; base = (size_t)9 << 20; }
    size_t off = e0 - base;
    f32x4 a = *(const f32x4*)(srcs[seg] + off);
    f32x4 b = *(const f32x4*)(srcs[seg] + off + 4);
    short8 o;
    o[0] = (short)f2bf(a[0]); o[1] = (short)f2bf(a[1]);
    o[2] = (short)f2bf(a[2]); o[3] = (short)f2bf(a[3]);
    o[4] = (short)f2bf(b[0]); o[5] = (short)f2bf(b[1]);
    o[6] = (short)f2bf(b[2]); o[7] = (short)f2bf(b[3]);
    *(short8*)(dsts[seg] + off) = o;
  } else {
    int j = blk - 5120;   // 0..3
    const float* bas[4] = { ba0, ba1, ba2, ba3 };
    const float* bbs[4] = { bb0, bb1, bb2, bb3 };
    float* bos[4] = { bo0, bo1, bo2, bo3 };
    int i0 = tid * 8;
    f32x4 x0 = *(const f32x4*)(bas[j] + i0);
    f32x4 x1 = *(const f32x4*)(bas[j] + i0 + 4);
    f32x4 y0 = *(const f32x4*)(bbs[j] + i0);
    f32x4 y1 = *(const f32x4*)(bbs[j] + i0 + 4);
    *(f32x4*)(bos[j] + i0) = x0 + y0;
    *(f32x4*)(bos[j] + i0 + 4) = x1 + y1;
  }
}

// ---------------- persistent bidirectional LSTM (+ fused pipeline stages) ----------------
// Worker protocol FROZEN (v11/v14; ledger: v11/v14 940-951 > v12 999 > v13 1158 >
// v15 HANG — poll liveness requires the cache-bypassing atomic flag load).
// v19 additions, both instances of v18's PROVEN heater-queue + flag-gate pattern:
//  mode 1 (layer 0): heaters first compute the xw0 GEMM tiles (queue 0..2047,
//    ends-first order, UNGATED — inputs ready pre-kernel), publishing each tile
//    via __syncthreads (vmcnt drain) + agent-scope RELEASE RMW on xq[dir][bm]
//    (G16 cross-XCD fence); then the xw1 tiles (queue 2048..4095, v18 logic).
//    Workers gate on xq: a pre-loop wait for the first tile, and lanes 32-63 of
//    the existing h-poll (previously redundant) check the NEXT tile's counter —
//    zero added serial latency; every xw read is issue-after-confirm.
//  mode 2 (layer 1): heaters compute FC rows per t (queue 0..255, middle-out),
//    gated on layer-1 flags >= {t+1, 256-t} with done>=64 escape (v18 gate).
__global__ __launch_bounds__(256, 1) void k_lstm(
    const unsigned short* __restrict__ xwF,   // [32 vs][8192][64] bf16 (permuted xw+bias)
    const unsigned short* __restrict__ xwB,
    const unsigned short* __restrict__ whF,   // [2048, 512] bf16
    const unsigned short* __restrict__ whB,
    unsigned short* __restrict__ hT,          // [2][256][16384] bf16 tiled (output)
    unsigned int* __restrict__ flags,         // [2][32][32] u32, zeroed
    unsigned int* __restrict__ done,          // 1 u32, zeroed
    int mode,                                 // 0 heat, 1 layer0 (+gemms), 2 layer1 (+fc)
    const unsigned short* __restrict__ xA,    // mode1: x_bf [8192,512]
    const unsigned short* __restrict__ gW0f, const unsigned short* __restrict__ gW0b,
    const float* __restrict__ gB0f, const float* __restrict__ gB0b,
    unsigned short* __restrict__ gC0f, unsigned short* __restrict__ gC0b,   // xw0 out
    const unsigned short* __restrict__ gW1f, const unsigned short* __restrict__ gW1b,
    const float* __restrict__ gB1f, const float* __restrict__ gB1b,
    unsigned short* __restrict__ gC1f, unsigned short* __restrict__ gC1b,   // xw1 out
    unsigned int* __restrict__ xq,            // xw0 tile counters [2][64]
    unsigned int* __restrict__ wq,            // queue counter
    const float* __restrict__ fcw,            // mode2: [20,1024]
    const float* __restrict__ fcb,            // mode2: [20]
    float* __restrict__ logits)               // mode2: [8192,20]
{
  const int wg = blockIdx.x;
  const int tid = threadIdx.x;

  __shared__ unsigned short Ws[64 * 512];   // 64KB
  __shared__ unsigned widx;

  if (wg >= 64) {
    // ---- heater / fused-stage worker ----
    asm volatile("s_setprio 0");
    if (mode == 1) {
      const int w = tid >> 6, lane = tid & 63;
      const int wr = w >> 1, wc = w & 1;
      const int lo = lane & 15, qd = lane >> 4;
      const int cis = (lane & 7) ^ (lane >> 3);
      for (;;) {
        if (tid == 0) widx = atomicAdd(wq, 1u);
        __syncthreads();
        unsigned idx = widx;
        __syncthreads();
        if (idx >= 4096u) break;
        if (idx < 2048u) {
          // ---- xw0 tile (K=512, A=x_bf), ends-first, ungated ----
          int j = (int)(idx >> 4), bn = (int)(idx & 15);
          int dir0 = j & 1;
          int bm = dir0 ? (63 - (j >> 1)) : (j >> 1);
          const unsigned short* Bw = dir0 ? gW0b : gW0f;
          const float* bias = dir0 ? gB0b : gB0f;
          unsigned short* Cq = dir0 ? gC0b : gC0f;
          f32x4 acc[4][4] = {};
          for (int kt = 0; kt < 8; ++kt) {
            __syncthreads();
#pragma unroll
            for (int p = 0; p < 4; ++p) {
              int rowb = w * 8 + p * 32;
              int row = rowb + (lane >> 3);
              GLD16(&xA[(size_t)(bm * 128 + row) * 512 + kt * 64 + cis * 8], &Ws[rowb * 64]);
              GLD16(&Bw[(size_t)(bn * 128 + row) * 512 + kt * 64 + cis * 8],
                    &Ws[8192 + rowb * 64]);
            }
            __syncthreads();
#pragma unroll
            for (int kk = 0; kk < 2; ++kk) {
              short8 af[4], bfr[4];
#pragma unroll
              for (int mi = 0; mi < 4; ++mi)
                af[mi] = *(const short8*)&Ws[(wr * 64 + mi * 16 + lo) * 64
                                             + (((kk * 4 + qd) ^ (lo & 7)) * 8)];
#pragma unroll
              for (int ni = 0; ni < 4; ++ni)
                bfr[ni] = *(const short8*)&Ws[8192 + (wc * 64 + ni * 16 + lo) * 64
                                              + (((kk * 4 + qd) ^ (lo & 7)) * 8)];
#pragma unroll
              for (int mi = 0; mi < 4; ++mi)
#pragma unroll
                for (int ni = 0; ni < 4; ++ni)
                  acc[mi][ni] = __builtin_amdgcn_mfma_f32_16x16x32_bf16(af[mi], bfr[ni], acc[mi][ni], 0, 0, 0);
            }
          }
#pragma unroll
          for (int mi = 0; mi < 4; ++mi) {
#pragma unroll
            for (int ni = 0; ni < 4; ++ni) {
              int n = bn * 128 + wc * 64 + ni * 16 + lo;
              float bv = bias[n];
              int wsb = (n >> 4) & 31, cg = n >> 9, jl = n & 15;
              size_t base = (size_t)wsb * (Rx * 64) + (size_t)cg * 16 + jl;
#pragma unroll
              for (int r2 = 0; r2 < 4; ++r2) {
                int m2 = bm * 128 + wr * 64 + mi * 16 + qd * 4 + r2;
                Cq[base + (size_t)m2 * 64] = f2bf(acc[mi][ni][r2] + bv);
              }
            }
          }
          __syncthreads();   // all threads' stores drained (vmcnt0 before barrier)
          if (tid == 0)
            __hip_atomic_fetch_add(xq + dir0 * 64 + bm, 1u,
                                   __ATOMIC_RELEASE, __HIP_MEMORY_SCOPE_AGENT);
        } else {
          // ---- xw1 tile (K=1024, A=h0T tiled), middle-out, h0-flag-gated (v18) ----
          unsigned idx2 = idx - 2048u;
          int r = (int)(idx2 >> 5), sub = (int)(idx2 & 31);
          int dir1 = sub >> 4, bn = sub & 15;
          int bm = (r & 1) ? (32 - ((r + 1) >> 1)) : (32 + (r >> 1));
          unsigned tF = (unsigned)(4 * bm + 4), tB = (unsigned)(256 - 4 * bm);
          if (tid < 64) {
            for (;;) {
              unsigned v = __hip_atomic_load(flags + (lane >> 5) * 1024 + (lane & 31) * 32,
                                             __ATOMIC_RELAXED, __HIP_MEMORY_SCOPE_AGENT);
              unsigned tgt = (lane < 32) ? tF : tB;
              if (__all((int)(v >= tgt))) break;
              if (__hip_atomic_load(done, __ATOMIC_RELAXED, __HIP_MEMORY_SCOPE_AGENT) >= 64u)
                break;
              float aa = 1.0f;
#pragma unroll 4
              for (int i = 0; i < 512; ++i) aa = __builtin_fmaf(aa, 1.0000001f, 1e-7f);
              asm volatile("" :: "v"(aa));
            }
          }
          __syncthreads();
          const unsigned short* Bw = dir1 ? gW1b : gW1f;
          const float* bias = dir1 ? gB1b : gB1f;
          unsigned short* Cq = dir1 ? gC1b : gC1f;
          f32x4 acc[4][4] = {};
          for (int kt = 0; kt < 16; ++kt) {
            __syncthreads();
#pragma unroll
            for (int p = 0; p < 4; ++p) {
              int rowb = w * 8 + p * 32;
              int row = rowb + (lane >> 3);
              int grow = bm * 128 + row;
              int t2 = grow >> 5, b2 = grow & 31;
              int k = kt * 64 + cis * 8;
              int dirx = k >> 9, kk2 = k & 511;
              GLD16(&hT[(size_t)dirx * (Sx * 16384) + (size_t)t2 * 16384
                        + (size_t)(kk2 >> 3) * 256 + b2 * 8], &Ws[rowb * 64]);
              GLD16(&Bw[(size_t)(bn * 128 + row) * 1024 + kt * 64 + cis * 8],
                    &Ws[8192 + rowb * 64]);
            }
            __syncthreads();
#pragma unroll
            for (int kk = 0; kk < 2; ++kk) {
              short8 af[4], bfr[4];
#pragma unroll
              for (int mi = 0; mi < 4; ++mi)
                af[mi] = *(const short8*)&Ws[(wr * 64 + mi * 16 + lo) * 64
                                             + (((kk * 4 + qd) ^ (lo & 7)) * 8)];
#pragma unroll
              for (int ni = 0; ni < 4; ++ni)
                bfr[ni] = *(const short8*)&Ws[8192 + (wc * 64 + ni * 16 + lo) * 64
                                              + (((kk * 4 + qd) ^ (lo & 7)) * 8)];
#pragma unroll
              for (int mi = 0; mi < 4; ++mi)
#pragma unroll
                for (int ni = 0; ni < 4; ++ni)
                  acc[mi][ni] = __builtin_amdgcn_mfma_f32_16x16x32_bf16(af[mi], bfr[ni], acc[mi][ni], 0, 0, 0);
            }
          }
#pragma unroll
          for (int mi = 0; mi < 4; ++mi) {
#pragma unroll
            for (int ni = 0; ni < 4; ++ni) {
              int n = bn * 128 + wc * 64 + ni * 16 + lo;
              float bv = bias[n];
              int wsb = (n >> 4) & 31, cg = n >> 9, jl = n & 15;
              size_t base = (size_t)wsb * (Rx * 64) + (size_t)cg * 16 + jl;
#pragma unroll
              for (int r2 = 0; r2 < 4; ++r2) {
                int m2 = bm * 128 + wr * 64 + mi * 16 + qd * 4 + r2;
                Cq[base + (size_t)m2 * 64] = f2bf(acc[mi][ni][r2] + bv);
              }
            }
          }
        }
        __syncthreads();
      }
    } else if (mode == 2) {
      // ---- FC worker: one t per queue item, middle-out, h1-flag-gated ----
      const int lane = tid & 63;
      for (;;) {
        if (tid == 0) widx = atomicAdd(wq, 1u);
        __syncthreads();
        unsigned idx = widx;
        __syncthreads();
        if (idx >= 256u) break;
        int r = (int)idx;
        int t = (r & 1) ? (127 - (r >> 1)) : (128 + (r >> 1));
        unsigned tF = (unsigned)(t + 1), tB = (unsigned)(Sx - t);
        if (tid < 64) {
          for (;;) {
            unsigned v = __hip_atomic_load(flags + (lane >> 5) * 1024 + (lane & 31) * 32,
                                           __ATOMIC_RELAXED, __HIP_MEMORY_SCOPE_AGENT);
            unsigned tgt = (lane < 32) ? tF : tB;
            if (__all((int)(v >= tgt))) break;
            if (__hip_atomic_load(done, __ATOMIC_RELAXED, __HIP_MEMORY_SCOPE_AGENT) >= 64u)
              break;
            float aa = 1.0f;
#pragma unroll 4
            for (int i = 0; i < 512; ++i) aa = __builtin_fmaf(aa, 1.0000001f, 1e-7f);
            asm volatile("" :: "v"(aa));
          }
        }
        __syncthreads();
        // stage h1[t] (both dirs, 64KB) into Ws; flag-gated cold-line plain loads
#pragma unroll
        for (int i = 0; i < 16; ++i) {
          int cidx = i * 256 + tid;            // 0..4095 chunks of 8 ushort
          int d2 = cidx >> 11, c2 = cidx & 2047;
          *(short8*)&Ws[cidx * 8] =
              *(const short8*)&hT[(size_t)d2 * (Sx * 16384) + (size_t)t * 16384
                                  + (size_t)c2 * 8];
        }
        __syncthreads();
        for (int o = tid; o < 640; o += 256) {
          int b2 = o / 20, l2 = o - b2 * 20;
          float accf = fcb[l2];
          for (int kc = 0; kc < 128; ++kc) {
            short8 hv = *(const short8*)&Ws[(((kc >> 6) * 2048) + (kc & 63) * 32 + b2) * 8];
            const float* wr2 = fcw + l2 * 1024 + (kc >> 6) * 512 + (kc & 63) * 8;
            accf += bf2f((unsigned short)hv[0]) * wr2[0] + bf2f((unsigned short)hv[1]) * wr2[1]
                  + bf2f((unsigned short)hv[2]) * wr2[2] + bf2f((unsigned short)hv[3]) * wr2[3]
                  + bf2f((unsigned short)hv[4]) * wr2[4] + bf2f((unsigned short)hv[5]) * wr2[5]
                  + bf2f((unsigned short)hv[6]) * wr2[6] + bf2f((unsigned short)hv[7]) * wr2[7];
          }
          logits[((size_t)t * 32 + b2) * 20 + l2] = accf;
        }
        __syncthreads();
      }
    }
    // ---- residual heat spin ----
    {
      float a = 1.0f + (float)tid, bm2 = 1.0000001f, cm = 1.0e-7f;
      for (;;) {
#pragma unroll 8
        for (int i = 0; i < 512; ++i) a = __builtin_fmaf(a, bm2, cm);
        if (__hip_atomic_load(done, __ATOMIC_RELAXED, __HIP_MEMORY_SCOPE_AGENT) >= 64u) break;
      }
      if (a == 123.456789f) ((volatile float*)hT)[0] = a;  // keep chain alive (never true)
    }
    return;
  }

  // ---- worker (round-4 proven protocol; v19 adds only the xw0 gate) ----
  asm volatile("s_setprio 3");
  const int dir = wg >> 5;
  const int vs = wg & 31;
  const int j0 = vs * 16;
  const unsigned short* xw = (dir ? xwB : xwF) + (size_t)vs * (Rx * 64);
  const unsigned short* wh = dir ? whB : whF;
  unsigned short* hTd = hT + (size_t)dir * (Sx * 16384);
  unsigned int* fl = flags + dir * 32 * 32;
  const unsigned int* xwc = xq ? (xq + dir * 64) : (const unsigned int*)0;

  // preload with all 256 threads: LDS row rr <- W row g=(rr>>4)*512+j0+(rr&15)
  {
    const int l6 = tid & 63;
#pragma unroll
    for (int i = 0; i < 16; ++i) {
      int rr = (tid >> 6) * 16 + i;
      int g = ((rr >> 4) << 9) + j0 + (rr & 15);
      int pc = l6 ^ (rr & 7);
      *(short8*)&Ws[rr * 512 + pc * 8] = *(const short8*)&wh[(size_t)g * Hx + l6 * 8];
    }
  }
  __syncthreads();
  if (tid >= 64) return;   // single worker wave continues (no further block barriers)

  const int lane = tid;           // 0..63
  const int bn = lane & 31;       // batch / MFMA n
  const int q  = lane >> 5;       // 0/1

  // v19 pre-loop gate: first xw0 tile (covers steps 0..3) must be published
  if (xwc) {
    unsigned v;
    do {
      v = __hip_atomic_load(xwc + (dir ? 63 : 0),
                            __ATOMIC_RELAXED, __HIP_MEMORY_SCOPE_AGENT);
    } while (v < 16u);
  }

  float cst[2][4] = {};

  for (int s = 0; s < Sx; ++s) {
    const int t = dir ? (Sx - 1 - s) : s;

    // prefetch xw (tile confirmed by pre-loop gate / previous step's poll)
    const unsigned short* xwt = xw + ((size_t)t * 32 + bn) * 64 + q * 4;
    unsigned long long xg[4][2];
#pragma unroll
    for (int c = 0; c < 4; ++c)
#pragma unroll
      for (int jg = 0; jg < 2; ++jg)
        xg[c][jg] = *(const unsigned long long*)(xwt + c * 16 + jg * 8);
    __asm__ __volatile__("" ::: "memory");

    f32x16 acc0, acc1;

    if (s > 0) {
      const unsigned tgt = (unsigned)s;
      const int tp = dir ? (t + 1) : (t - 1);
      const unsigned short* hb = hTd + (size_t)tp * 16384 + lane * 8;

      // v11 speculative poll — atomic flag load first (cache-bypassing:
      // liveness), then all 32 plain b128 h loads, one combined wait
      // (keep-alives), then check. v19: lanes 32-63 (previously redundant)
      // additionally gate the NEXT xw0 tile's counter — zero added latency.
      short8 hreg[32];
      for (;;) {
        unsigned v, tgt2;
        if (lane < 32 || !xwc) {
          v = __hip_atomic_load(fl + (lane & 31) * 32,
                                __ATOMIC_RELAXED, __HIP_MEMORY_SCOPE_AGENT);
          tgt2 = tgt;
        } else {
          int sn = (s + 1 < Sx) ? (s + 1) : (Sx - 1);
          int tn = dir ? (Sx - 1 - sn) : sn;
          v = __hip_atomic_load(xwc + (tn >> 2),
                                __ATOMIC_RELAXED, __HIP_MEMORY_SCOPE_AGENT);
          tgt2 = 16u;
        }
#pragma unroll
        for (int ks = 0; ks < 32; ++ks)
          hreg[ks] = *(const short8*)(hb + ks * 512);   // flag-gated plain b128
#pragma unroll
        for (int ks = 0; ks < 32; ++ks)
          asm volatile("" :: "v"(hreg[ks]));            // pin loads inside loop
        if (__all((int)(v >= tgt2))) break;
        __asm__ __volatile__("" ::: "memory");          // force re-load on retry
      }
      __builtin_amdgcn_sched_barrier(0);

      f32x16 a0 = {}, a1 = {}, b0 = {}, b1 = {};   // 4 independent chains
#pragma unroll
      for (int ks = 0; ks < 32; ks += 2) {
        int lc0 = ks * 2 + q, lc1 = (ks + 1) * 2 + q;
        int pc0 = lc0 ^ (bn & 7), pc1 = lc1 ^ (bn & 7);
        short8 af00 = *(const short8*)&Ws[bn * 512 + pc0 * 8];
        short8 af10 = *(const short8*)&Ws[(32 + bn) * 512 + pc0 * 8];
        short8 af01 = *(const short8*)&Ws[bn * 512 + pc1 * 8];
        short8 af11 = *(const short8*)&Ws[(32 + bn) * 512 + pc1 * 8];
        a0 = __builtin_amdgcn_mfma_f32_32x32x16_bf16(af00, hreg[ks],     a0, 0, 0, 0);
        a1 = __builtin_amdgcn_mfma_f32_32x32x16_bf16(af10, hreg[ks],     a1, 0, 0, 0);
        b0 = __builtin_amdgcn_mfma_f32_32x32x16_bf16(af01, hreg[ks + 1], b0, 0, 0, 0);
        b1 = __builtin_amdgcn_mfma_f32_32x32x16_bf16(af11, hreg[ks + 1], b1, 0, 0, 0);
      }
      acc0 = a0 + b0;
      acc1 = a1 + b1;
    } else {
      acc0 = (f32x16){};
      acc1 = (f32x16){};
    }

    // epilogue: lane (bn,q) computes h for batch bn, j = j0 + jg*8 + q*4 + r
#pragma unroll
    for (int jg = 0; jg < 2; ++jg) {
      unsigned long long hv = 0;
#pragma unroll
      for (int r = 0; r < 4; ++r) {
        float iv = acc0[jg * 4 + r]     + bfh(xg[0][jg], r);
        float fv = acc0[8 + jg * 4 + r] + bfh(xg[1][jg], r);
        float gv = acc1[jg * 4 + r]     + bfh(xg[2][jg], r);
        float ov = acc1[8 + jg * 4 + r] + bfh(xg[3][jg], r);
        float ct = fsigm(fv) * cst[jg][r] + fsigm(iv) * ftanh(gv);
        cst[jg][r] = ct;
        float hvf = fsigm(ov) * ftanh(ct);
        hv |= (unsigned long long)f2bf(hvf) << (16 * r);
      }
      // hT[t][vs*2+jg][bn][q*4..q*4+3] — write-through to coherence point
      unsigned short* hw = hTd + (size_t)t * 16384 + ((size_t)(vs * 2 + jg) * 32 + bn) * 8 + q * 4;
      __hip_atomic_store((unsigned long long*)hw, hv,
                         __ATOMIC_RELAXED, __HIP_MEMORY_SCOPE_AGENT);
    }

    // drain sc1 stores to the coherence point, then publish own flag
    __asm__ __volatile__("s_waitcnt vmcnt(0)" ::: "memory");
    if (lane == 0)
      __hip_atomic_store(fl + vs * 32, (unsigned)(s + 1),
                         __ATOMIC_RELAXED, __HIP_MEMORY_SCOPE_AGENT);
  }

  if (lane == 0)
    __hip_atomic_fetch_add(done, 1u, __ATOMIC_RELAXED, __HIP_MEMORY_SCOPE_AGENT);
}

// ---------------- CRF ----------------
__global__ __launch_bounds__(64) void k_crf(
    const float* __restrict__ logits,   // [(t*32+b)*20 + l]
    const int* __restrict__ labels,     // [B,S]
    const int* __restrict__ mask,       // [B,S]
    const float* __restrict__ trans,    // [20,20]
    const float* __restrict__ startv,
    const float* __restrict__ endv,
    float* __restrict__ out)
{
  int b = blockIdx.x;
  int tid = threadIdx.x;
  __shared__ float tr[Lx * Lx];
  __shared__ float al[2][Lx];
  __shared__ float norm_s;
  for (int i = tid; i < Lx * Lx; i += 64) tr[i] = trans[i];
  if (tid < Lx) al[0][tid] = logits[b * Lx + tid] + startv[tid];
  __syncthreads();
  int cur = 0;
  float em = (tid < Lx) ? logits[((size_t)1 * Bx + b) * Lx + tid] : 0.f;
  int m = mask[b * Sx + 1];
  for (int t = 1; t < Sx; ++t) {
    float em_next = 0.f;
    int m_next = 0;
    if (t + 1 < Sx) {
      if (tid < Lx) em_next = logits[((size_t)(t + 1) * Bx + b) * Lx + tid];
      m_next = mask[b * Sx + t + 1];
    }
    if (tid < Lx) {
      int to = tid;
      float v[Lx];
      float mx = -1e30f;
#pragma unroll
      for (int f = 0; f < Lx; ++f) { v[f] = al[cur][f] + tr[f * Lx + to]; mx = fmaxf(mx, v[f]); }
      float sum = 0.f;
#pragma unroll
      for (int f = 0; f < Lx; ++f) sum += __builtin_amdgcn_exp2f((v[f] - mx) * L2E);
      float nv = mx + LN2 * __builtin_amdgcn_logf(sum) + em;
      al[1 - cur][to] = (m > 0) ? nv : al[cur][to];
    }
    __syncthreads();
    cur ^= 1;
    em = em_next;
    m = m_next;
  }
  if (tid == 0) {
    float mx = -1e30f;
    for (int l = 0; l < Lx; ++l) mx = fmaxf(mx, al[cur][l] + endv[l]);
    float s = 0.f;
    for (int l = 0; l < Lx; ++l) s += __builtin_amdgcn_exp2f((al[cur][l] + endv[l] - mx) * L2E);
    norm_s = mx + LN2 * __builtin_amdgcn_logf(s);
  }
  __syncthreads();
  const int* lab = labels + b * Sx;
  const int* msk = mask + b * Sx;
  float part = 0.f;
  int msum = 0;
  for (int t = tid; t < Sx; t += 64) {
    int mm = msk[t];
    int tg = lab[t];
    if (mm > 0) {
      part += logits[((size_t)t * Bx + b) * Lx + tg];
      if (t >= 1) part += tr[lab[t - 1] * Lx + tg];
      msum++;
    }
  }
#pragma unroll
  for (int o = 32; o > 0; o >>= 1) {
    part += __shfl_down(part, o, 64);
    msum += __shfl_down(msum, o, 64);
  }
  if (tid == 0) {
    float gold = part + startv[lab[0]] + endv[lab[msum - 1]];
    atomicAdd(out, (norm_s - gold) * (1.0f / 32.0f));
  }
}

// ---------------- launch ----------------

extern "C" void kernel_launch(void* const* d_in, const int* in_sizes, int n_in,
                              void* d_out, int out_size, void* d_ws, size_t ws_size,
                              hipStream_t stream)
{
  const float* x      = (const float*)d_in[0];
  const int* labels   = (const int*)d_in[1];
  const int* mask     = (const int*)d_in[2];
  const float* wih0f  = (const float*)d_in[3];
  const float* whh0f  = (const float*)d_in[4];
  const float* bih0f  = (const float*)d_in[5];
  const float* bhh0f  = (const float*)d_in[6];
  const float* wih0b  = (const float*)d_in[7];
  const float* whh0b  = (const float*)d_in[8];
  const float* bih0b  = (const float*)d_in[9];
  const float* bhh0b  = (const float*)d_in[10];
  const float* wih1f  = (const float*)d_in[11];
  const float* whh1f  = (const float*)d_in[12];
  const float* bih1f  = (const float*)d_in[13];
  const float* bhh1f  = (const float*)d_in[14];
  const float* wih1b  = (const float*)d_in[15];
  const float* whh1b  = (const float*)d_in[16];
  const float* bih1b  = (const float*)d_in[17];
  const float* bhh1b  = (const float*)d_in[18];
  const float* fcw    = (const float*)d_in[19];
  const float* fcb    = (const float*)d_in[20];
  const float* transm = (const float*)d_in[21];
  const float* startv = (const float*)d_in[22];
  const float* endv   = (const float*)d_in[23];

  char* p = (char*)d_ws;
  auto alloc = [&](size_t bytes) -> char* {
    char* r = p;
    p += (bytes + 255) & ~((size_t)255);
    return r;
  };

  unsigned short* x_bf    = (unsigned short*)alloc((size_t)Rx * Hx * 2);
  unsigned short* wih0f_b = (unsigned short*)alloc((size_t)Gx * Hx * 2);
  unsigned short* wih0b_b = (unsigned short*)alloc((size_t)Gx * Hx * 2);
  unsigned short* whh0f_b = (unsigned short*)alloc((size_t)Gx * Hx * 2);
  unsigned short* whh0b_b = (unsigned short*)alloc((size_t)Gx * Hx * 2);
  unsigned short* wih1f_b = (unsigned short*)alloc((size_t)Gx * 1024 * 2);
  unsigned short* wih1b_b = (unsigned short*)alloc((size_t)Gx * 1024 * 2);
  unsigned short* whh1f_b = (unsigned short*)alloc((size_t)Gx * Hx * 2);
  unsigned short* whh1b_b = (unsigned short*)alloc((size_t)Gx * Hx * 2);
  float* bias0f = (float*)alloc(Gx * 4);
  float* bias0b = (float*)alloc(Gx * 4);
  float* bias1f = (float*)alloc(Gx * 4);
  float* bias1b = (float*)alloc(Gx * 4);
  unsigned short* xw_f  = (unsigned short*)alloc((size_t)Rx * Gx * 2);
  unsigned short* xw_b  = (unsigned short*)alloc((size_t)Rx * Gx * 2);
  unsigned short* xw1_f = (unsigned short*)alloc((size_t)Rx * Gx * 2);
  unsigned short* xw1_b = (unsigned short*)alloc((size_t)Rx * Gx * 2);
  unsigned short* h0T  = (unsigned short*)alloc((size_t)2 * Sx * 16384 * 2);
  unsigned short* h1T  = (unsigned short*)alloc((size_t)2 * Sx * 16384 * 2);
  float* logits = (float*)alloc((size_t)Rx * Lx * 4);
  unsigned int* flagsA = (unsigned int*)alloc(2 * 32 * 32 * 4);
  unsigned int* flagsB = (unsigned int*)alloc(2 * 32 * 32 * 4);
  unsigned int* doneA  = (unsigned int*)alloc(256);
  unsigned int* doneB  = (unsigned int*)alloc(256);
  unsigned int* wq     = (unsigned int*)alloc(512);   // [0]=layer0 queue, [64]=layer1 queue
  unsigned int* xwcnt  = (unsigned int*)alloc(2 * 64 * 4);

  if ((size_t)(p - (char*)d_ws) > ws_size) return;

  hipMemsetAsync(flagsA, 0, 2 * 32 * 32 * 4, stream);
  hipMemsetAsync(flagsB, 0, 2 * 32 * 32 * 4, stream);
  hipMemsetAsync(doneA, 0, 256, stream);
  hipMemsetAsync(doneB, 0, 256, stream);
  hipMemsetAsync(wq, 0, 512, stream);
  hipMemsetAsync(xwcnt, 0, 2 * 64 * 4, stream);

  // pack input + fused weight-cast/bias prep
  k_pack_x<<<(Rx * Hx) / 256, 256, 0, stream>>>(x, x_bf);
  k_prep<<<5124, 256, 0, stream>>>(
      wih0f, wih0b, whh0f, whh0b, wih1f, wih1b, whh1f, whh1b,
      wih0f_b, wih0b_b, whh0f_b, whh0b_b, wih1f_b, wih1b_b, whh1f_b, whh1b_b,
      bih0f, bhh0f, bias0f,
      bih0b, bhh0b, bias0b,
      bih1f, bhh1f, bias1f,
      bih1b, bhh1b, bias1b);

  // layer 0: heaters produce xw0 (ends-first, release-fenced) then xw1 (v18)
  k_lstm<<<256, 256, 0, stream>>>(xw_f, xw_b, whh0f_b, whh0b_b, h0T, flagsA, doneA, 1,
                                  x_bf, wih0f_b, wih0b_b, bias0f, bias0b, xw_f, xw_b,
                                  wih1f_b, wih1b_b, bias1f, bias1b, xw1_f, xw1_b,
                                  xwcnt, wq,
                                  (const float*)nullptr, (const float*)nullptr,
                                  (float*)nullptr);

  // layer 1: heaters compute FC as h1 becomes ready
  k_lstm<<<256, 256, 0, stream>>>(xw1_f, xw1_b, whh1f_b, whh1b_b, h1T, flagsB, doneB, 2,
                                  (const unsigned short*)nullptr,
                                  (const unsigned short*)nullptr, (const unsigned short*)nullptr,
                                  (const float*)nullptr, (const float*)nullptr,
                                  (unsigned short*)nullptr, (unsigned short*)nullptr,
                                  (const unsigned short*)nullptr, (const unsigned short*)nullptr,
                                  (const float*)nullptr, (const float*)nullptr,
                                  (unsigned short*)nullptr, (unsigned short*)nullptr,
                                  (unsigned int*)nullptr, wq + 64,
                                  fcw, fcb, logits);

  // CRF
  hipMemsetAsync(d_out, 0, 4, stream);
  k_crf<<<Bx, 64, 0, stream>>>(logits, labels, mask, transm, startv, endv, (float*)d_out);
}

// Round 14
// 2426.316 us; speedup vs baseline: 1.0175x; 1.0175x over previous
//
#include <hip/hip_runtime.h>

// Problem constants
#define Sx 256
#define Bx 32
#define Hx 512
#define Gx 2048   // 4H
#define Lx 20
#define Rx 8192   // S*B

typedef __attribute__((ext_vector_type(8))) short short8;
typedef __attribute__((ext_vector_type(4))) float f32x4;
typedef __attribute__((ext_vector_type(16))) float f32x16;

__device__ __forceinline__ unsigned short f2bf(float f) {
  union { float f; unsigned u; } v; v.f = f;
  unsigned u = v.u;
  return (unsigned short)((u + 0x7fffu + ((u >> 16) & 1u)) >> 16);
}
__device__ __forceinline__ float bf2f(unsigned short h) {
  union { unsigned u; float f; } v; v.u = ((unsigned)h) << 16;
  return v.f;
}
__device__ __forceinline__ float bfh(unsigned long long x, int r) {
  return bf2f((unsigned short)((x >> (16 * r)) & 0xffffull));
}

// hardware transcendentals (v11+): ~3 ulp composite, orders below bf16 noise
__device__ __forceinline__ float fsigm(float x) {
  return __builtin_amdgcn_rcpf(1.0f + __builtin_amdgcn_exp2f(-1.44269504f * x));
}
__device__ __forceinline__ float ftanh(float x) {
  return __builtin_fmaf(-2.0f,
      __builtin_amdgcn_rcpf(1.0f + __builtin_amdgcn_exp2f(2.88539008f * x)), 1.0f);
}
#define L2E 1.44269504088896f
#define LN2 0.69314718055995f

// v17: async global->LDS staging, 16B per lane; XOR chunk-swizzle on both the
// per-lane global source and the ds_read chunk index (verified absmax 0.0).
#define GLD16(gp, lp) __builtin_amdgcn_global_load_lds( \
    (const __attribute__((address_space(1))) void*)(gp), \
    (__attribute__((address_space(3))) void*)(lp), 16, 0, 0)

// ---------------- pack / prep kernels ----------------

__global__ void k_pack_x(const float* __restrict__ x, unsigned short* __restrict__ xbf) {
  int tid = blockIdx.x * 256 + threadIdx.x;      // 0 .. S*B*H-1
  int h = tid & (Hx - 1);
  int r = tid >> 9;          // t*32+b
  int b = r & 31;
  int t = r >> 5;
  xbf[tid] = f2bf(x[(b * Sx + t) * Hx + h]);
}

// v16: single fused prep — all 8 weight casts (10M elems, 8/thread) + the 4
// bias adds. Segment table in 1M-element units: [0,1,2,3,4,6,8,9,10].
__global__ __launch_bounds__(256) void k_prep(
    const float* __restrict__ s0, const float* __restrict__ s1,
    const float* __restrict__ s2, const float* __restrict__ s3,
    const float* __restrict__ s4, const float* __restrict__ s5,
    const float* __restrict__ s6, const float* __restrict__ s7,
    unsigned short* __restrict__ d0, unsigned short* __restrict__ d1,
    unsigned short* __restrict__ d2, unsigned short* __restrict__ d3,
    unsigned short* __restrict__ d4, unsigned short* __restrict__ d5,
    unsigned short* __restrict__ d6, unsigned short* __restrict__ d7,
    const float* __restrict__ ba0, const float* __restrict__ bb0, float* __restrict__ bo0,
    const float* __restrict__ ba1, const float* __restrict__ bb1, float* __restrict__ bo1,
    const float* __restrict__ ba2, const float* __restrict__ bb2, float* __restrict__ bo2,
    const float* __restrict__ ba3, const float* __restrict__ bb3, float* __restrict__ bo3)
{
  const int blk = blockIdx.x;
  const int tid = threadIdx.x;
  if (blk < 5120) {
    const float* srcs[8] = { s0, s1, s2, s3, s4, s5, s6, s7 };
    unsigned short* dsts[8] = { d0, d1, d2, d3, d4, d5, d6, d7 };
    size_t e0 = ((size_t)blk * 256 + tid) * 8;
    int m = (int)(e0 >> 20);
    int seg; size_t base;
    if (m < 4)      { seg = m; base = (size_t)m << 20; }
    else if (m < 6) { seg = 4; base = (size_t)4 << 20; }
    else if (m < 8) { seg = 5; base = (size_t)6 << 20; }
    else if (m == 8){ seg = 6; base = (size_t)8 << 20; }
    else            { seg = 7; base = (size_t)9 << 20; }
    size_t off = e0 - base;
    f32x4 a = *(const f32x4*)(srcs[seg] + off);
    f32x4 b = *(const f32x4*)(srcs[seg] + off + 4);
    short8 o;
    o[0] = (short)f2bf(a[0]); o[1] = (short)f2bf(a[1]);
    o[2] = (short)f2bf(a[2]); o[3] = (short)f2bf(a[3]);
    o[4] = (short)f2bf(b[0]); o[5] = (short)f2bf(b[1]);
    o[6] = (short)f2bf(b[2]); o[7] = (short)f2bf(b[3]);
    *(short8*)(dsts[seg] + off) = o;
  } else {
    int j = blk - 5120;   // 0..3
    const float* bas[4] = { ba0, ba1, ba2, ba3 };
    const float* bbs[4] = { bb0, bb1, bb2, bb3 };
    float* bos[4] = { bo0, bo1, bo2, bo3 };
    int i0 = tid * 8;
    f32x4 x0 = *(const f32x4*)(bas[j] + i0);
    f32x4 x1 = *(const f32x4*)(bas[j] + i0 + 4);
    f32x4 y0 = *(const f32x4*)(bbs[j] + i0);
    f32x4 y1 = *(const f32x4*)(bbs[j] + i0 + 4);
    *(f32x4*)(bos[j] + i0) = x0 + y0;
    *(f32x4*)(bos[j] + i0 + 4) = x1 + y1;
  }
}

// ---------------- GEMM (layer 0): xw[perm(n)][m] = A[M,K] * Bw[N,K]^T + bias[N] ----------------
// v17: global_load_lds staging + XOR chunk swizzle (verified).
__global__ __launch_bounds__(256) void k_gemm(
    const unsigned short* __restrict__ A,
    const unsigned short* __restrict__ Bw,
    const float* __restrict__ bias,
    unsigned short* __restrict__ C,
    int M, int N, int K)
{
  const int bn = blockIdx.x, bm = blockIdx.y;
  const int tid = threadIdx.x;
  const int w = tid >> 6, lane = tid & 63;
  const int wr = w >> 1, wc = w & 1;
  const int lo = lane & 15, qd = lane >> 4;

  __shared__ unsigned short As[128 * 64];   // 16KB, linear (no pad)
  __shared__ unsigned short Bs[128 * 64];

  f32x4 acc[4][4] = {};

  const int cis = (lane & 7) ^ (lane >> 3);
  const int ktn = K >> 6;
  for (int kt = 0; kt < ktn; ++kt) {
    __syncthreads();
#pragma unroll
    for (int p = 0; p < 4; ++p) {
      int rowb = w * 8 + p * 32;              // wave-uniform row base
      int row = rowb + (lane >> 3);
      GLD16(&A[(size_t)(bm * 128 + row) * K + kt * 64 + cis * 8], &As[rowb * 64]);
      GLD16(&Bw[(size_t)(bn * 128 + row) * K + kt * 64 + cis * 8], &Bs[rowb * 64]);
    }
    __syncthreads();
#pragma unroll
    for (int kk = 0; kk < 2; ++kk) {
      short8 af[4], bfr[4];
#pragma unroll
      for (int mi = 0; mi < 4; ++mi)
        af[mi] = *(const short8*)&As[(wr * 64 + mi * 16 + lo) * 64
                                     + (((kk * 4 + qd) ^ (lo & 7)) * 8)];
#pragma unroll
      for (int ni = 0; ni < 4; ++ni)
        bfr[ni] = *(const short8*)&Bs[(wc * 64 + ni * 16 + lo) * 64
                                      + (((kk * 4 + qd) ^ (lo & 7)) * 8)];
#pragma unroll
      for (int mi = 0; mi < 4; ++mi)
#pragma unroll
        for (int ni = 0; ni < 4; ++ni)
          acc[mi][ni] = __builtin_amdgcn_mfma_f32_16x16x32_bf16(af[mi], bfr[ni], acc[mi][ni], 0, 0, 0);
    }
  }
#pragma unroll
  for (int mi = 0; mi < 4; ++mi) {
#pragma unroll
    for (int ni = 0; ni < 4; ++ni) {
      int n = bn * 128 + wc * 64 + ni * 16 + lo;
      float bv = bias[n];
      int wsb = (n >> 4) & 31, cg = n >> 9, jl = n & 15;
      size_t base = (size_t)wsb * (Rx * 64) + (size_t)cg * 16 + jl;
#pragma unroll
      for (int r = 0; r < 4; ++r) {
        int m = bm * 128 + wr * 64 + mi * 16 + qd * 4 + r;
        C[base + (size_t)m * 64] = f2bf(acc[mi][ni][r] + bv);
      }
    }
  }
}

// ---------------- persistent bidirectional LSTM recurrence ----------------
// v20 = EXACT v18 (best measured: 2431us total, PASSED Round 11). Worker
// protocol FROZEN (v11/v14; ledger: v11/v14 940-951 > v12 999 > v13 1158 >
// v15 HANG — poll liveness requires the cache-bypassing ATOMIC flag load).
// Heater blocks in layer 0 compute the layer-1 xw GEMM tiles (v18's proven
// +70us net win). Fusion ledger: xw1-into-lstm0 POSITIVE (keep);
// xw0-into-lstm0 NEGATIVE; FC-into-lstm1 NEGATIVE. Do not extend further.
__global__ __launch_bounds__(256, 1) void k_lstm(
    const unsigned short* __restrict__ xwF,   // [32 vs][8192][64] bf16 (permuted xw+bias)
    const unsigned short* __restrict__ xwB,
    const unsigned short* __restrict__ whF,   // [2048, 512] bf16
    const unsigned short* __restrict__ whB,
    unsigned short* __restrict__ hT,          // [2][256][16384] bf16 tiled (output)
    unsigned int* __restrict__ flags,         // [2][32][32] u32, zeroed
    unsigned int* __restrict__ done,          // 1 u32, zeroed
    const unsigned short* __restrict__ gWf,   // heater-GEMM: wih1f bf16 [2048,1024]
    const unsigned short* __restrict__ gWb,   //              wih1b
    const float* __restrict__ gBf,            //              bias1f
    const float* __restrict__ gBb,            //              bias1b
    unsigned short* __restrict__ gCf,         //              xw1_f out (permuted)
    unsigned short* __restrict__ gCb,         //              xw1_b out
    unsigned int* __restrict__ wq,            //              tile queue counter
    int gw)                                   //              1 = do gemm work
{
  const int wg = blockIdx.x;
  const int tid = threadIdx.x;

  __shared__ unsigned short Ws[64 * 512];   // 64KB (worker: weights; heater: As/Bs)
  __shared__ unsigned widx;

  if (wg >= 64) {
    // ---- heater / layer-1 GEMM worker ----
    asm volatile("s_setprio 0");
    if (gw) {
      const int w = tid >> 6, lane = tid & 63;
      const int wr = w >> 1, wc = w & 1;
      const int lo = lane & 15, qd = lane >> 4;
      const int cis = (lane & 7) ^ (lane >> 3);
      for (;;) {
        if (tid == 0) widx = atomicAdd(wq, 1u);
        __syncthreads();
        unsigned idx = widx;
        __syncthreads();
        if (idx >= 2048u) break;
        int r = (int)(idx >> 5), sub = (int)(idx & 31);
        int dir1 = sub >> 4, bn = sub & 15;
        int bm = (r & 1) ? (32 - ((r + 1) >> 1)) : (32 + (r >> 1));
        unsigned tF = (unsigned)(4 * bm + 4), tB = (unsigned)(256 - 4 * bm);
        if (tid < 64) {
          for (;;) {
            unsigned v = __hip_atomic_load(flags + (lane >> 5) * 1024 + (lane & 31) * 32,
                                           __ATOMIC_RELAXED, __HIP_MEMORY_SCOPE_AGENT);
            unsigned tgt = (lane < 32) ? tF : tB;
            if (__all((int)(v >= tgt))) break;
            if (__hip_atomic_load(done, __ATOMIC_RELAXED, __HIP_MEMORY_SCOPE_AGENT) >= 64u)
              break;   // workers finished => everything is ready
            float aa = 1.0f;
#pragma unroll 4
            for (int i = 0; i < 512; ++i) aa = __builtin_fmaf(aa, 1.0000001f, 1e-7f);
            asm volatile("" :: "v"(aa));   // ~2000cy backoff, keeps clocks hot
          }
        }
        __syncthreads();
        // ---- verified v17 gemm_t tile body (As=Ws[0..8191], Bs=Ws[8192..16383]) ----
        const unsigned short* Bw = dir1 ? gWb : gWf;
        const float* bias = dir1 ? gBb : gBf;
        unsigned short* Cq = dir1 ? gCb : gCf;
        f32x4 acc[4][4] = {};
        for (int kt = 0; kt < 16; ++kt) {
          __syncthreads();
#pragma unroll
          for (int p = 0; p < 4; ++p) {
            int rowb = w * 8 + p * 32;
            int row = rowb + (lane >> 3);
            int grow = bm * 128 + row;
            int t2 = grow >> 5, b2 = grow & 31;
            int k = kt * 64 + cis * 8;
            int dirx = k >> 9, kk2 = k & 511;
            GLD16(&hT[(size_t)dirx * (Sx * 16384) + (size_t)t2 * 16384
                      + (size_t)(kk2 >> 3) * 256 + b2 * 8], &Ws[rowb * 64]);
            GLD16(&Bw[(size_t)(bn * 128 + row) * 1024 + kt * 64 + cis * 8],
                  &Ws[8192 + rowb * 64]);
          }
          __syncthreads();
#pragma unroll
          for (int kk = 0; kk < 2; ++kk) {
            short8 af[4], bfr[4];
#pragma unroll
            for (int mi = 0; mi < 4; ++mi)
              af[mi] = *(const short8*)&Ws[(wr * 64 + mi * 16 + lo) * 64
                                           + (((kk * 4 + qd) ^ (lo & 7)) * 8)];
#pragma unroll
            for (int ni = 0; ni < 4; ++ni)
              bfr[ni] = *(const short8*)&Ws[8192 + (wc * 64 + ni * 16 + lo) * 64
                                            + (((kk * 4 + qd) ^ (lo & 7)) * 8)];
#pragma unroll
            for (int mi = 0; mi < 4; ++mi)
#pragma unroll
              for (int ni = 0; ni < 4; ++ni)
                acc[mi][ni] = __builtin_amdgcn_mfma_f32_16x16x32_bf16(af[mi], bfr[ni], acc[mi][ni], 0, 0, 0);
          }
        }
#pragma unroll
        for (int mi = 0; mi < 4; ++mi) {
#pragma unroll
          for (int ni = 0; ni < 4; ++ni) {
            int n = bn * 128 + wc * 64 + ni * 16 + lo;
            float bv = bias[n];
            int wsb = (n >> 4) & 31, cg = n >> 9, jl = n & 15;
            size_t base = (size_t)wsb * (Rx * 64) + (size_t)cg * 16 + jl;
#pragma unroll
            for (int r2 = 0; r2 < 4; ++r2) {
              int m2 = bm * 128 + wr * 64 + mi * 16 + qd * 4 + r2;
              Cq[base + (size_t)m2 * 64] = f2bf(acc[mi][ni][r2] + bv);
            }
          }
        }
        __syncthreads();
      }
    }
    // ---- residual heat spin ----
    {
      float a = 1.0f + (float)tid, bm2 = 1.0000001f, cm = 1.0e-7f;
      for (;;) {
#pragma unroll 8
        for (int i = 0; i < 512; ++i) a = __builtin_fmaf(a, bm2, cm);
        if (__hip_atomic_load(done, __ATOMIC_RELAXED, __HIP_MEMORY_SCOPE_AGENT) >= 64u) break;
      }
      if (a == 123.456789f) ((volatile float*)hT)[0] = a;  // keep chain alive (never true)
    }
    return;
  }

  // ---- worker (round-4 proven protocol, FROZEN) ----
  asm volatile("s_setprio 3");
  const int dir = wg >> 5;
  const int vs = wg & 31;
  const int j0 = vs * 16;
  const unsigned short* xw = (dir ? xwB : xwF) + (size_t)vs * (Rx * 64);
  const unsigned short* wh = dir ? whB : whF;
  unsigned short* hTd = hT + (size_t)dir * (Sx * 16384);
  unsigned int* fl = flags + dir * 32 * 32;

  // preload with all 256 threads: LDS row rr <- W row g=(rr>>4)*512+j0+(rr&15)
  {
    const int l6 = tid & 63;
#pragma unroll
    for (int i = 0; i < 16; ++i) {
      int rr = (tid >> 6) * 16 + i;
      int g = ((rr >> 4) << 9) + j0 + (rr & 15);
      int pc = l6 ^ (rr & 7);
      *(short8*)&Ws[rr * 512 + pc * 8] = *(const short8*)&wh[(size_t)g * Hx + l6 * 8];
    }
  }
  __syncthreads();
  if (tid >= 64) return;   // single worker wave continues (no further block barriers)

  const int lane = tid;           // 0..63
  const int bn = lane & 31;       // batch / MFMA n
  const int q  = lane >> 5;       // 0/1

  float cst[2][4] = {};

  for (int s = 0; s < Sx; ++s) {
    const int t = dir ? (Sx - 1 - s) : s;

    // prefetch xw (contiguous per-slice block; plain loads) before the poll
    const unsigned short* xwt = xw + ((size_t)t * 32 + bn) * 64 + q * 4;
    unsigned long long xg[4][2];
#pragma unroll
    for (int c = 0; c < 4; ++c)
#pragma unroll
      for (int jg = 0; jg < 2; ++jg)
        xg[c][jg] = *(const unsigned long long*)(xwt + c * 16 + jg * 8);
    __asm__ __volatile__("" ::: "memory");

    f32x16 acc0, acc1;

    if (s > 0) {
      const unsigned tgt = (unsigned)s;
      const int tp = dir ? (t + 1) : (t - 1);
      const unsigned short* hb = hTd + (size_t)tp * 16384 + lane * 8;

      // v11 speculative poll — atomic flag load first (cache-bypassing:
      // liveness), then all 32 plain b128 h loads, one combined wait
      // (keep-alives), then check. On success the h data is already in VGPRs.
      short8 hreg[32];
      for (;;) {
        unsigned v = __hip_atomic_load(fl + (lane & 31) * 32,
                                       __ATOMIC_RELAXED, __HIP_MEMORY_SCOPE_AGENT);
#pragma unroll
        for (int ks = 0; ks < 32; ++ks)
          hreg[ks] = *(const short8*)(hb + ks * 512);   // flag-gated plain b128
#pragma unroll
        for (int ks = 0; ks < 32; ++ks)
          asm volatile("" :: "v"(hreg[ks]));            // pin loads inside loop
        if (__all((int)(v >= tgt))) break;
        __asm__ __volatile__("" ::: "memory");          // force re-load on retry
      }
      __builtin_amdgcn_sched_barrier(0);

      f32x16 a0 = {}, a1 = {}, b0 = {}, b1 = {};   // 4 independent chains
#pragma unroll
      for (int ks = 0; ks < 32; ks += 2) {
        int lc0 = ks * 2 + q, lc1 = (ks + 1) * 2 + q;
        int pc0 = lc0 ^ (bn & 7), pc1 = lc1 ^ (bn & 7);
        short8 af00 = *(const short8*)&Ws[bn * 512 + pc0 * 8];
        short8 af10 = *(const short8*)&Ws[(32 + bn) * 512 + pc0 * 8];
        short8 af01 = *(const short8*)&Ws[bn * 512 + pc1 * 8];
        short8 af11 = *(const short8*)&Ws[(32 + bn) * 512 + pc1 * 8];
        a0 = __builtin_amdgcn_mfma_f32_32x32x16_bf16(af00, hreg[ks],     a0, 0, 0, 0);
        a1 = __builtin_amdgcn_mfma_f32_32x32x16_bf16(af10, hreg[ks],     a1, 0, 0, 0);
        b0 = __builtin_amdgcn_mfma_f32_32x32x16_bf16(af01, hreg[ks + 1], b0, 0, 0, 0);
        b1 = __builtin_amdgcn_mfma_f32_32x32x16_bf16(af11, hreg[ks + 1], b1, 0, 0, 0);
      }
      acc0 = a0 + b0;
      acc1 = a1 + b1;
    } else {
      acc0 = (f32x16){};
      acc1 = (f32x16){};
    }

    // epilogue: lane (bn,q) computes h for batch bn, j = j0 + jg*8 + q*4 + r
#pragma unroll
    for (int jg = 0; jg < 2; ++jg) {
      unsigned long long hv = 0;
#pragma unroll
      for (int r = 0; r < 4; ++r) {
        float iv = acc0[jg * 4 + r]     + bfh(xg[0][jg], r);
        float fv = acc0[8 + jg * 4 + r] + bfh(xg[1][jg], r);
        float gv = acc1[jg * 4 + r]     + bfh(xg[2][jg], r);
        float ov = acc1[8 + jg * 4 + r] + bfh(xg[3][jg], r);
        float ct = fsigm(fv) * cst[jg][r] + fsigm(iv) * ftanh(gv);
        cst[jg][r] = ct;
        float hvf = fsigm(ov) * ftanh(ct);
        hv |= (unsigned long long)f2bf(hvf) << (16 * r);
      }
      // hT[t][vs*2+jg][bn][q*4..q*4+3] — write-through to coherence point
      unsigned short* hw = hTd + (size_t)t * 16384 + ((size_t)(vs * 2 + jg) * 32 + bn) * 8 + q * 4;
      __hip_atomic_store((unsigned long long*)hw, hv,
                         __ATOMIC_RELAXED, __HIP_MEMORY_SCOPE_AGENT);
    }

    // drain sc1 stores to the coherence point, then publish own flag
    __asm__ __volatile__("s_waitcnt vmcnt(0)" ::: "memory");
    if (lane == 0)
      __hip_atomic_store(fl + vs * 32, (unsigned)(s + 1),
                         __ATOMIC_RELAXED, __HIP_MEMORY_SCOPE_AGENT);
  }

  if (lane == 0)
    __hip_atomic_fetch_add(done, 1u, __ATOMIC_RELAXED, __HIP_MEMORY_SCOPE_AGENT);
}

// ---------------- FC: logits[row,l] = dot(h1T[row,:1024], fc_w[l,:]) + fc_b[l] ----------------
__global__ __launch_bounds__(256) void k_fc(
    const unsigned short* __restrict__ h1T,  // [2][256][16384] tiled
    const float* __restrict__ fcw,           // [20,1024]
    const float* __restrict__ fcb,           // [20]
    float* __restrict__ logits)              // [8192,20]
{
  int row = blockIdx.x;
  int t = row >> 5, b = row & 31;
  int l = threadIdx.x & 31;
  int sl = threadIdx.x >> 5;   // 0..7
  __shared__ float red[8][32];
  float p = 0.f;
  if (l < Lx) {
#pragma unroll 4
    for (int kt = sl * 16; kt < sl * 16 + 16; ++kt) {   // 8-elem groups, k = kt*8
      int k = kt * 8;
      int dir = k >> 9, kk = k & 511;
      const unsigned short* hp = h1T + (size_t)dir * (Sx * 16384) + (size_t)t * 16384
                                 + ((size_t)(kk >> 3) * 32 + b) * 8;
      short8 hv = *(const short8*)hp;
      const float* wr = fcw + l * 1024 + k;
      f32x4 w0 = *(const f32x4*)wr;
      f32x4 w1 = *(const f32x4*)(wr + 4);
      p += bf2f((unsigned short)hv[0]) * w0[0] + bf2f((unsigned short)hv[1]) * w0[1]
         + bf2f((unsigned short)hv[2]) * w0[2] + bf2f((unsigned short)hv[3]) * w0[3]
         + bf2f((unsigned short)hv[4]) * w1[0] + bf2f((unsigned short)hv[5]) * w1[1]
         + bf2f((unsigned short)hv[6]) * w1[2] + bf2f((unsigned short)hv[7]) * w1[3];
    }
  }
  red[sl][l] = p;
  __syncthreads();
  if (threadIdx.x < Lx) {
    float s = fcb[threadIdx.x];
#pragma unroll
    for (int i = 0; i < 8; ++i) s += red[i][threadIdx.x];
    logits[(size_t)row * Lx + threadIdx.x] = s;
  }
}

// ---------------- CRF ----------------
__global__ __launch_bounds__(64) void k_crf(
    const float* __restrict__ logits,   // [(t*32+b)*20 + l]
    const int* __restrict__ labels,     // [B,S]
    const int* __restrict__ mask,       // [B,S]
    const float* __restrict__ trans,    // [20,20]
    const float* __restrict__ startv,
    const float* __restrict__ endv,
    float* __restrict__ out)
{
  int b = blockIdx.x;
  int tid = threadIdx.x;
  __shared__ float tr[Lx * Lx];
  __shared__ float al[2][Lx];
  __shared__ float norm_s;
  for (int i = tid; i < Lx * Lx; i += 64) tr[i] = trans[i];
  if (tid < Lx) al[0][tid] = logits[b * Lx + tid] + startv[tid];
  __syncthreads();
  int cur = 0;
  float em = (tid < Lx) ? logits[((size_t)1 * Bx + b) * Lx + tid] : 0.f;
  int m = mask[b * Sx + 1];
  for (int t = 1; t < Sx; ++t) {
    float em_next = 0.f;
    int m_next = 0;
    if (t + 1 < Sx) {
      if (tid < Lx) em_next = logits[((size_t)(t + 1) * Bx + b) * Lx + tid];
      m_next = mask[b * Sx + t + 1];
    }
    if (tid < Lx) {
      int to = tid;
      float v[Lx];
      float mx = -1e30f;
#pragma unroll
      for (int f = 0; f < Lx; ++f) { v[f] = al[cur][f] + tr[f * Lx + to]; mx = fmaxf(mx, v[f]); }
      float sum = 0.f;
#pragma unroll
      for (int f = 0; f < Lx; ++f) sum += __builtin_amdgcn_exp2f((v[f] - mx) * L2E);
      float nv = mx + LN2 * __builtin_amdgcn_logf(sum) + em;
      al[1 - cur][to] = (m > 0) ? nv : al[cur][to];
    }
    __syncthreads();
    cur ^= 1;
    em = em_next;
    m = m_next;
  }
  if (tid == 0) {
    float mx = -1e30f;
    for (int l = 0; l < Lx; ++l) mx = fmaxf(mx, al[cur][l] + endv[l]);
    float s = 0.f;
    for (int l = 0; l < Lx; ++l) s += __builtin_amdgcn_exp2f((al[cur][l] + endv[l] - mx) * L2E);
    norm_s = mx + LN2 * __builtin_amdgcn_logf(s);
  }
  __syncthreads();
  const int* lab = labels + b * Sx;
  const int* msk = mask + b * Sx;
  float part = 0.f;
  int msum = 0;
  for (int t = tid; t < Sx; t += 64) {
    int mm = msk[t];
    int tg = lab[t];
    if (mm > 0) {
      part += logits[((size_t)t * Bx + b) * Lx + tg];
      if (t >= 1) part += tr[lab[t - 1] * Lx + tg];
      msum++;
    }
  }
#pragma unroll
  for (int o = 32; o > 0; o >>= 1) {
    part += __shfl_down(part, o, 64);
    msum += __shfl_down(msum, o, 64);
  }
  if (tid == 0) {
    float gold = part + startv[lab[0]] + endv[lab[msum - 1]];
    atomicAdd(out, (norm_s - gold) * (1.0f / 32.0f));
  }
}

// ---------------- launch ----------------

extern "C" void kernel_launch(void* const* d_in, const int* in_sizes, int n_in,
                              void* d_out, int out_size, void* d_ws, size_t ws_size,
                              hipStream_t stream)
{
  const float* x      = (const float*)d_in[0];
  const int* labels   = (const int*)d_in[1];
  const int* mask     = (const int*)d_in[2];
  const float* wih0f  = (const float*)d_in[3];
  const float* whh0f  = (const float*)d_in[4];
  const float* bih0f  = (const float*)d_in[5];
  const float* bhh0f  = (const float*)d_in[6];
  const float* wih0b  = (const float*)d_in[7];
  const float* whh0b  = (const float*)d_in[8];
  const float* bih0b  = (const float*)d_in[9];
  const float* bhh0b  = (const float*)d_in[10];
  const float* wih1f  = (const float*)d_in[11];
  const float* whh1f  = (const float*)d_in[12];
  const float* bih1f  = (const float*)d_in[13];
  const float* bhh1f  = (const float*)d_in[14];
  const float* wih1b  = (const float*)d_in[15];
  const float* whh1b  = (const float*)d_in[16];
  const float* bih1b  = (const float*)d_in[17];
  const float* bhh1b  = (const float*)d_in[18];
  const float* fcw    = (const float*)d_in[19];
  const float* fcb    = (const float*)d_in[20];
  const float* transm = (const float*)d_in[21];
  const float* startv = (const float*)d_in[22];
  const float* endv   = (const float*)d_in[23];

  char* p = (char*)d_ws;
  auto alloc = [&](size_t bytes) -> char* {
    char* r = p;
    p += (bytes + 255) & ~((size_t)255);
    return r;
  };

  unsigned short* x_bf    = (unsigned short*)alloc((size_t)Rx * Hx * 2);
  unsigned short* wih0f_b = (unsigned short*)alloc((size_t)Gx * Hx * 2);
  unsigned short* wih0b_b = (unsigned short*)alloc((size_t)Gx * Hx * 2);
  unsigned short* whh0f_b = (unsigned short*)alloc((size_t)Gx * Hx * 2);
  unsigned short* whh0b_b = (unsigned short*)alloc((size_t)Gx * Hx * 2);
  unsigned short* wih1f_b = (unsigned short*)alloc((size_t)Gx * 1024 * 2);
  unsigned short* wih1b_b = (unsigned short*)alloc((size_t)Gx * 1024 * 2);
  unsigned short* whh1f_b = (unsigned short*)alloc((size_t)Gx * Hx * 2);
  unsigned short* whh1b_b = (unsigned short*)alloc((size_t)Gx * Hx * 2);
  float* bias0f = (float*)alloc(Gx * 4);
  float* bias0b = (float*)alloc(Gx * 4);
  float* bias1f = (float*)alloc(Gx * 4);
  float* bias1b = (float*)alloc(Gx * 4);
  unsigned short* xw_f  = (unsigned short*)alloc((size_t)Rx * Gx * 2);
  unsigned short* xw_b  = (unsigned short*)alloc((size_t)Rx * Gx * 2);
  unsigned short* xw1_f = (unsigned short*)alloc((size_t)Rx * Gx * 2);
  unsigned short* xw1_b = (unsigned short*)alloc((size_t)Rx * Gx * 2);
  unsigned short* h0T  = (unsigned short*)alloc((size_t)2 * Sx * 16384 * 2);
  unsigned short* h1T  = (unsigned short*)alloc((size_t)2 * Sx * 16384 * 2);
  float* logits = (float*)alloc((size_t)Rx * Lx * 4);
  unsigned int* flagsA = (unsigned int*)alloc(2 * 32 * 32 * 4);
  unsigned int* flagsB = (unsigned int*)alloc(2 * 32 * 32 * 4);
  unsigned int* doneA  = (unsigned int*)alloc(256);
  unsigned int* doneB  = (unsigned int*)alloc(256);
  unsigned int* wq     = (unsigned int*)alloc(256);

  if ((size_t)(p - (char*)d_ws) > ws_size) return;

  hipMemsetAsync(flagsA, 0, 2 * 32 * 32 * 4, stream);
  hipMemsetAsync(flagsB, 0, 2 * 32 * 32 * 4, stream);
  hipMemsetAsync(doneA, 0, 256, stream);
  hipMemsetAsync(doneB, 0, 256, stream);
  hipMemsetAsync(wq, 0, 256, stream);

  // pack input + fused weight-cast/bias prep
  k_pack_x<<<(Rx * Hx) / 256, 256, 0, stream>>>(x, x_bf);
  k_prep<<<5124, 256, 0, stream>>>(
      wih0f, wih0b, whh0f, whh0b, wih1f, wih1b, whh1f, whh1b,
      wih0f_b, wih0b_b, whh0f_b, whh0b_b, wih1f_b, wih1b_b, whh1f_b, whh1b_b,
      bih0f, bhh0f, bias0f,
      bih0b, bhh0b, bias0b,
      bih1f, bhh1f, bias1f,
      bih1b, bhh1b, bias1b);

  // layer 0 input GEMMs
  k_gemm<<<dim3(Gx / 128, Rx / 128), 256, 0, stream>>>(x_bf, wih0f_b, bias0f, xw_f, Rx, Gx, Hx);
  k_gemm<<<dim3(Gx / 128, Rx / 128), 256, 0, stream>>>(x_bf, wih0b_b, bias0b, xw_b, Rx, Gx, Hx);

  // layer 0 lstm; heater blocks compute the layer-1 xw GEMMs as h0 becomes ready
  k_lstm<<<256, 256, 0, stream>>>(xw_f, xw_b, whh0f_b, whh0b_b, h0T, flagsA, doneA,
                                  wih1f_b, wih1b_b, bias1f, bias1b, xw1_f, xw1_b, wq, 1);

  // layer 1 lstm (xw1 already computed in-flight); heaters are pure heaters
  k_lstm<<<256, 256, 0, stream>>>(xw1_f, xw1_b, whh1f_b, whh1b_b, h1T, flagsB, doneB,
                                  (const unsigned short*)nullptr, (const unsigned short*)nullptr,
                                  (const float*)nullptr, (const float*)nullptr,
                                  (unsigned short*)nullptr, (unsigned short*)nullptr,
                                  (unsigned int*)nullptr, 0);

  // FC + CRF
  k_fc<<<Rx, 256, 0, stream>>>(h1T, fcw, fcb, logits);
  hipMemsetAsync(d_out, 0, 4, stream);
  k_crf<<<Bx, 64, 0, stream>>>(logits, labels, mask, transm, startv, endv, (float*)d_out);
}